// Round 8
// baseline (181.606 us; speedup 1.0000x reference)
//
#include <hip/hip_runtime.h>
#include <hip/hip_bf16.h>
#include <stdint.h>

// Problem constants (from reference setup_inputs)
#define BATCH 8
#define TC 2048   // M
#define TQ 1024   // K
#define DD 1024   // N

typedef __attribute__((ext_vector_type(8))) __bf16 bf16x8;
typedef __attribute__((ext_vector_type(4))) float f32x4;
typedef __attribute__((ext_vector_type(16))) float f32x16;
typedef __attribute__((ext_vector_type(8))) ushort ushort8v;

__device__ __forceinline__ ushort f2bf(float f) {
    uint32_t u = __float_as_uint(f);
    uint32_t r = (u + 0x7fffu + ((u >> 16) & 1u)) >> 16;  // RNE
    return (ushort)r;
}

// ---------------------------------------------------------------------------
// Kernel 1 (prep v4, UNCHANGED from R7): prep investigation CLOSED -- four
// structures (split / sequential-fused / interleaved / pipelined-persistent)
// all land 44-48us for this 144MB read-modify-write shape.
//   blocks [0,512):   softmax, 4 waves x 2 rows x 4 iters, 1-deep prefetch
//   blocks [512,1024): transpose, 4 tiles/block, prefetch across syncthreads
// ---------------------------------------------------------------------------
__global__ __launch_bounds__(256) void prep3(const float* __restrict__ sim,
                                             const float* __restrict__ qen,
                                             ushort* __restrict__ attn,
                                             ushort* __restrict__ qt) {
    __shared__ float tile[64][65];
    const int t = threadIdx.x;
    if (blockIdx.x < 512) {
        // ---- softmax: 2 rows/wave/iter, 4 iters, 1-deep prefetch ----
        const int wid = t >> 6, lane = t & 63;
        const int pair0 = blockIdx.x * 16 + wid * 4;       // 4 consecutive pairs
        const float4* sp = (const float4*)(sim + (size_t)pair0 * 2 * TQ);
        ushort4* dp = (ushort4*)(attn + (size_t)pair0 * 2 * TQ);
        const float L2E = 1.4426950408889634f;

        float4 x0[4], x1[4], n0[4], n1[4];
        #pragma unroll
        for (int j = 0; j < 4; j++) {
            x0[j] = sp[lane + 64 * j];
            x1[j] = sp[256 + lane + 64 * j];
        }

        #pragma unroll
        for (int n = 0; n < 4; n++) {
            if (n < 3) {
                const float4* np = sp + 512;
                #pragma unroll
                for (int j = 0; j < 4; j++) {
                    n0[j] = np[lane + 64 * j];
                    n1[j] = np[256 + lane + 64 * j];
                }
            }

            float m0 = -INFINITY, m1 = -INFINITY;
            #pragma unroll
            for (int j = 0; j < 4; j++) {
                m0 = fmaxf(m0, fmaxf(fmaxf(x0[j].x, x0[j].y), fmaxf(x0[j].z, x0[j].w)));
                m1 = fmaxf(m1, fmaxf(fmaxf(x1[j].x, x1[j].y), fmaxf(x1[j].z, x1[j].w)));
            }
            #pragma unroll
            for (int o = 32; o >= 1; o >>= 1) {
                m0 = fmaxf(m0, __shfl_xor(m0, o));
                m1 = fmaxf(m1, __shfl_xor(m1, o));
            }

            float sa = 0.f, sb = 0.f;
            #pragma unroll
            for (int j = 0; j < 4; j++) {
                x0[j].x = exp2f((x0[j].x - m0) * L2E);
                x0[j].y = exp2f((x0[j].y - m0) * L2E);
                x0[j].z = exp2f((x0[j].z - m0) * L2E);
                x0[j].w = exp2f((x0[j].w - m0) * L2E);
                sa += (x0[j].x + x0[j].y) + (x0[j].z + x0[j].w);
                x1[j].x = exp2f((x1[j].x - m1) * L2E);
                x1[j].y = exp2f((x1[j].y - m1) * L2E);
                x1[j].z = exp2f((x1[j].z - m1) * L2E);
                x1[j].w = exp2f((x1[j].w - m1) * L2E);
                sb += (x1[j].x + x1[j].y) + (x1[j].z + x1[j].w);
            }
            #pragma unroll
            for (int o = 32; o >= 1; o >>= 1) {
                sa += __shfl_xor(sa, o);
                sb += __shfl_xor(sb, o);
            }
            const float iva = 1.0f / sa, ivb = 1.0f / sb;

            #pragma unroll
            for (int j = 0; j < 4; j++) {
                ushort4 o4;
                o4.x = f2bf(x0[j].x * iva);
                o4.y = f2bf(x0[j].y * iva);
                o4.z = f2bf(x0[j].z * iva);
                o4.w = f2bf(x0[j].w * iva);
                dp[lane + 64 * j] = o4;
                o4.x = f2bf(x1[j].x * ivb);
                o4.y = f2bf(x1[j].y * ivb);
                o4.z = f2bf(x1[j].z * ivb);
                o4.w = f2bf(x1[j].w * ivb);
                dp[256 + lane + 64 * j] = o4;
            }

            sp += 512;
            dp += 512;
            if (n < 3) {
                #pragma unroll
                for (int j = 0; j < 4; j++) { x0[j] = n0[j]; x1[j] = n1[j]; }
            }
        }
    } else {
        // ---- transpose+cast: 4 tiles/block, prefetch across the LDS phase ----
        const int tb = blockIdx.x - 512;
        const int r = t >> 4;               // 0..15
        const int c = (t & 15) * 4;         // 0..60
        const int dl = t >> 4;              // output d sub-index
        const int qq = (t & 15) * 4;

        float4 v[4], v2[4];
        {
            const int tile_i = tb * 4;
            const int b = tile_i >> 8;
            const int rem = tile_i & 255;
            const int q0 = (rem >> 4) * 64;
            const int d0 = (rem & 15) * 64;
            #pragma unroll
            for (int it = 0; it < 4; it++)
                v[it] = *(const float4*)(qen + ((size_t)b * TQ + q0 + r + it * 16) * DD + d0 + c);
        }

        #pragma unroll
        for (int n = 0; n < 4; n++) {
            const int tile_i = tb * 4 + n;
            const int b = tile_i >> 8;
            const int rem = tile_i & 255;
            const int q0 = (rem >> 4) * 64;
            const int d0 = (rem & 15) * 64;

            #pragma unroll
            for (int it = 0; it < 4; it++) {
                tile[r + it * 16][c + 0] = v[it].x;
                tile[r + it * 16][c + 1] = v[it].y;
                tile[r + it * 16][c + 2] = v[it].z;
                tile[r + it * 16][c + 3] = v[it].w;
            }

            if (n < 3) {
                const int tj = tile_i + 1;
                const int b2 = tj >> 8;
                const int rem2 = tj & 255;
                const int q02 = (rem2 >> 4) * 64;
                const int d02 = (rem2 & 15) * 64;
                #pragma unroll
                for (int it = 0; it < 4; it++)
                    v2[it] = *(const float4*)(qen + ((size_t)b2 * TQ + q02 + r + it * 16) * DD + d02 + c);
            }

            __syncthreads();

            #pragma unroll
            for (int it = 0; it < 4; it++) {
                const int d = dl + it * 16;
                ushort4 o4;
                o4.x = f2bf(tile[qq + 0][d]);
                o4.y = f2bf(tile[qq + 1][d]);
                o4.z = f2bf(tile[qq + 2][d]);
                o4.w = f2bf(tile[qq + 3][d]);
                *(ushort4*)(qt + ((size_t)b * DD + d0 + d) * TQ + q0 + qq) = o4;
            }

            if (n < 3) {
                __syncthreads();   // protect LDS overwrite next iter
                #pragma unroll
                for (int it = 0; it < 4; it++) v[it] = v2[it];
            }
        }
    }
}

// ---------------------------------------------------------------------------
// Kernel 2: batched GEMM  C[b] = A[b] (MxK bf16) x Bt[b]^T (NxK bf16)
// R8 change (ONLY): MFMA shape 16x16x32 -> 32x32x16.  Same 128x128 tile,
// BK=64, 4 waves, same staging swizzle, same barriers.  Per K-step:
// 16 MFMA (was 32) at the higher 32x32 rate (2382 vs 2075 TF ubench) and
// same 16 ds_read_b128.  Fragment layouts (family-consistent, C/D verified
// in guide m74/m101):
//   A/B input: row = lane&31, k = (lane>>5)*8 + i   (8 bf16 = 4 VGPR)
//   C/D:       col = lane&31, row = (reg&3) + 8*(reg>>2) + 4*(lane>>5)
// Swizzle algebra unchanged: frag rows = base + l32 with base % 32 == 0, so
// row&7 = l32&7; read chunk = (ks*2 + (lane>>5)) ^ (l32&7).  Per-inst bank
// spread identical to the proven 16x16 version (8 lanes/16B slot, 2-way).
// C stores: per reg, 2 x 128B contiguous segments (better than 4 x 64B).
// Batch-per-XCD decode (b = flat&7) kept from R4.
// ---------------------------------------------------------------------------
__global__ __launch_bounds__(256, 2) void gemm_bf16(const ushort* __restrict__ A,
                                                    const ushort* __restrict__ Bt,
                                                    float* __restrict__ C) {
    __shared__ __align__(16) ushort As[128 * 64];   // 16 KiB
    __shared__ __align__(16) ushort Bs[128 * 64];   // 16 KiB

    const int flat = blockIdx.x;
    const int b = flat & 7;           // batch = XCD (dispatch round-robin)
    const int rem = flat >> 3;        // 0..127: 16 m-tiles x 8 n-tiles
    const int group = rem >> 5;       // 4 groups of 32 blocks
    const int mi_t = group * 4 + (rem & 3);
    const int ni_t = (rem >> 2) & 7;
    const int tm0 = mi_t * 128;
    const int tn0 = ni_t * 128;

    const ushort* Ab = A + (size_t)b * TC * TQ;
    const ushort* Bb = Bt + (size_t)b * DD * TQ;
    float* Cb = C + (size_t)b * TC * DD;

    const int t = threadIdx.x;
    const int w = t >> 6, lane = t & 63;
    const int l32 = lane & 31;        // fragment row within 32-row block
    const int hi = lane >> 5;         // k-half selector
    const int wm = (w >> 1) * 64, wn = (w & 1) * 64;

    f32x16 acc[2][2];
    #pragma unroll
    for (int i = 0; i < 2; i++)
        #pragma unroll
        for (int j = 0; j < 2; j++)
            #pragma unroll
            for (int e = 0; e < 16; e++) acc[i][j][e] = 0.f;

    // staging (unchanged): chunk idx = i*256 + w*64 + lane; row = i*32+w*8+(lane>>3)
    // slot-chunk xs = lane&7; fetch global chunk c = xs ^ (row&7)
    const int srow = w * 8 + (lane >> 3);
    const int sk = ((lane & 7) ^ (lane >> 3)) * 8;   // ushort offset in k

    // fragment read: row = base + l32 (base % 32 == 0) -> row&7 = l32&7
    const int rkey = l32 & 7;

    for (int kk = 0; kk < TQ; kk += 64) {
        #pragma unroll
        for (int i = 0; i < 4; i++) {
            const ushort* ga = Ab + (size_t)(tm0 + i * 32 + srow) * TQ + kk + sk;
            const ushort* gb = Bb + (size_t)(tn0 + i * 32 + srow) * TQ + kk + sk;
            char* la = (char*)As + i * 4096 + w * 1024;
            char* lb = (char*)Bs + i * 4096 + w * 1024;
            __builtin_amdgcn_global_load_lds(
                (const __attribute__((address_space(1))) void*)ga,
                (__attribute__((address_space(3))) void*)la, 16, 0, 0);
            __builtin_amdgcn_global_load_lds(
                (const __attribute__((address_space(1))) void*)gb,
                (__attribute__((address_space(3))) void*)lb, 16, 0, 0);
        }
        __syncthreads();

        #pragma unroll
        for (int ks = 0; ks < 4; ks++) {
            const int cswz = ((ks * 2 + hi) ^ rkey) * 8;   // ushort offset in k
            bf16x8 a0 = *(const bf16x8*)&As[(wm +  0 + l32) * 64 + cswz];
            bf16x8 a1 = *(const bf16x8*)&As[(wm + 32 + l32) * 64 + cswz];
            bf16x8 b0 = *(const bf16x8*)&Bs[(wn +  0 + l32) * 64 + cswz];
            bf16x8 b1 = *(const bf16x8*)&Bs[(wn + 32 + l32) * 64 + cswz];

            acc[0][0] = __builtin_amdgcn_mfma_f32_32x32x16_bf16(a0, b0, acc[0][0], 0, 0, 0);
            acc[0][1] = __builtin_amdgcn_mfma_f32_32x32x16_bf16(a0, b1, acc[0][1], 0, 0, 0);
            acc[1][0] = __builtin_amdgcn_mfma_f32_32x32x16_bf16(a1, b0, acc[1][0], 0, 0, 0);
            acc[1][1] = __builtin_amdgcn_mfma_f32_32x32x16_bf16(a1, b1, acc[1][1], 0, 0, 0);
        }
        __syncthreads();
    }

    // epilogue: C/D layout col = l32, row = (reg&3) + 8*(reg>>2) + 4*hi
    #pragma unroll
    for (int mi = 0; mi < 2; mi++) {
        const int rbase = tm0 + wm + mi * 32 + 4 * hi;
        #pragma unroll
        for (int ni = 0; ni < 2; ni++) {
            const int c = tn0 + wn + ni * 32 + l32;
            f32x16 v = acc[mi][ni];
            #pragma unroll
            for (int r = 0; r < 16; r++) {
                const int row = rbase + (r & 3) + 8 * (r >> 2);
                Cb[(size_t)row * DD + c] = v[r];
            }
        }
    }
}

// ---------------------------------------------------------------------------
extern "C" void kernel_launch(void* const* d_in, const int* in_sizes, int n_in,
                              void* d_out, int out_size, void* d_ws, size_t ws_size,
                              hipStream_t stream) {
    const float* sim = (const float*)d_in[0];   // [8, 2048, 1024]
    const float* qen = (const float*)d_in[1];   // [8, 1024, 1024]
    float* out = (float*)d_out;                 // [8, 2048, 1024]

    ushort* attn = (ushort*)d_ws;                                  // 32 MiB bf16
    ushort* qt = (ushort*)d_ws + (size_t)BATCH * TC * TQ;          // 16 MiB bf16

    prep3<<<512 + 512, 256, 0, stream>>>(sim, qen, attn, qt);
    gemm_bf16<<<BATCH * (TC / 128) * (DD / 128), 256, 0, stream>>>(attn, qt, out);
}